// Round 3
// baseline (2099.698 us; speedup 1.0000x reference)
//
#include <hip/hip_runtime.h>
#include <hip/hip_bf16.h>

// ECLGCNN: ChebConv(K=3) on 49152 disjoint 32-node graphs -> per-sample BN ->
// sigmoid -> LSTM(48 steps, H=512) -> linear head.
// Inputs fp32, edge_index int32, OUTPUT fp32 (round-2 evidence: bf16 output
// writes covered only half of out_nbytes -> upper half zeros -> stub-identical
// absmax). Internal compute: fp32 graph/BN, bf16 MFMA LSTM.

#define B_    1024
#define T_    48
#define NPG_  32
#define F_    5
#define H_    512
#define EPG_  256
#define NG_   (B_*T_)          // 49152 graphs
#define N_    (B_*T_*NPG_)     // 1572864 nodes
#define E_    (B_*T_*EPG_)     // 12582912 edges
#define NF_   (N_*F_)          // 7864320

typedef __bf16 bf16x8 __attribute__((ext_vector_type(8)));
typedef float  f32x4  __attribute__((ext_vector_type(4)));
typedef __hip_bfloat16 bf16;

__device__ __forceinline__ float sigm(float x)   { return 1.0f/(1.0f+__expf(-x)); }
__device__ __forceinline__ float tanh_f(float x) { return 2.0f/(1.0f+__expf(-2.0f*x)) - 1.0f; }

__global__ __launch_bounds__(256) void k_zero(float4* p, int n) {
    int i = blockIdx.x*256 + threadIdx.x;
    if (i < n) p[i] = make_float4(0.f, 0.f, 0.f, 0.f);
}

// fp32 -> bf16 weight conversion (n multiple of 4)
__global__ __launch_bounds__(256) void k_cvt(const float* __restrict__ src, bf16* __restrict__ dst, int n) {
    int i = (blockIdx.x*256 + threadIdx.x)*4;
    if (i < n) {
        float4 v = *reinterpret_cast<const float4*>(src + i);
        dst[i]   = __float2bfloat16(v.x);
        dst[i+1] = __float2bfloat16(v.y);
        dst[i+2] = __float2bfloat16(v.z);
        dst[i+3] = __float2bfloat16(v.w);
    }
}

// One block per 32-node graph. Edges are graph-local (node = g*32 + local, so local = idx&31).
__global__ __launch_bounds__(256) void k_graph(
    const float* __restrict__ x, const float* __restrict__ ea,
    const float* __restrict__ cW, const float* __restrict__ cb,
    const int* __restrict__ ei, float* __restrict__ y_pre,
    float* __restrict__ bn_acc)
{
    const int g = blockIdx.x, tid = threadIdx.x;
    __shared__ float deg[32], dinv[32];
    __shared__ float T0[160], T1[160], T2[160], W[75], bch[5], vbuf[160];
    const int e = g*EPG_ + tid;
    const int s = ei[e] & 31;          // src local
    const int d = ei[E_ + e] & 31;     // dst local
    const float w = ea[e];
    if (tid < 75) W[tid]  = cW[tid];
    if (tid < 5)  bch[tid] = cb[tid];
    if (tid < 32) deg[tid] = 0.f;
    if (tid < 160) { T0[tid] = x[(size_t)g*160 + tid]; T1[tid] = 0.f; T2[tid] = 0.f; }
    __syncthreads();
    atomicAdd(&deg[s], w);             // deg = segment_sum(edge_attr, src)
    __syncthreads();
    if (tid < 32) dinv[tid] = deg[tid] > 0.f ? rsqrtf(deg[tid]) : 0.f;
    __syncthreads();
    const float nrm = -dinv[s] * w * dinv[d];
    #pragma unroll
    for (int f = 0; f < 5; ++f) atomicAdd(&T1[d*5+f], nrm * T0[s*5+f]);   // T1 = L~ x
    __syncthreads();
    #pragma unroll
    for (int f = 0; f < 5; ++f) atomicAdd(&T2[d*5+f], nrm * T1[s*5+f]);   // spmm(T1)
    __syncthreads();
    if (tid < 160) T2[tid] = 2.f*T2[tid] - T0[tid];                        // T2 = 2 L~ T1 - T0
    __syncthreads();
    if (tid < 160) {
        const int n = tid/5, f = tid - 5*n;
        float v = bch[f];
        #pragma unroll
        for (int c = 0; c < 5; ++c)
            v += T0[n*5+c]*W[c*5+f] + T1[n*5+c]*W[25+c*5+f] + T2[n*5+c]*W[50+c*5+f];
        y_pre[(size_t)g*160 + tid] = v;
        vbuf[tid] = v;
    }
    __syncthreads();
    if (tid < 10) {    // per-graph BN partials -> per-sample atomics (sample = g/48)
        const int f = tid % 5; const bool sq = tid >= 5;
        float sm = 0.f;
        for (int n = 0; n < 32; ++n) { float v = vbuf[n*5+f]; sm += sq ? v*v : v; }
        atomicAdd(&bn_acc[(g/T_)*10 + (sq ? 5 : 0) + f], sm);
    }
}

// BN apply + sigmoid; writes X (bf16) in [T][B][160] layout so each LSTM step reads contiguously.
__global__ __launch_bounds__(256) void k_bn(
    const float* __restrict__ y_pre, const float* __restrict__ bn_acc,
    const float* __restrict__ gamma, const float* __restrict__ beta,
    bf16* __restrict__ X)
{
    const int i = blockIdx.x*256 + threadIdx.x;     // exactly NF_ threads
    const int b   = i / 7680;                        // 7680 = T*NPG*F
    const int rem = i - b*7680;
    const int t   = rem / 160;
    const int pf  = rem - t*160;
    const int f   = pf % 5;
    const float inv  = 1.0f/1536.0f;
    const float mean = bn_acc[b*10+f]*inv;
    const float var  = bn_acc[b*10+5+f]*inv - mean*mean;
    const float v = gamma[f]*(y_pre[i]-mean)*rsqrtf(var+1e-5f) + beta[f];
    X[((size_t)t*B_ + b)*160 + pf] = __float2bfloat16(sigm(v));
}

// One LSTM step: gates[1024,2048] = [X_t | h] @ [W_ih | W_hh]^T, fused pointwise epilogue.
// Block = 64 rows(b) x 16 units(u) x all 4 gates. Grid (16, 32) = 512 blocks.
// NT-layout mfma_f32_16x16x32_bf16: A[m=lane&15][k=quad*8+j], B[n=lane&15][k=quad*8+j],
// C/D: col(=n)=lane&15, row(=m)=quad*4+reg.
__global__ __launch_bounds__(256) void k_step(
    const bf16* __restrict__ Xt,  const bf16* __restrict__ Wih,
    const bf16* __restrict__ Whh, const float* __restrict__ bih,
    const float* __restrict__ bhh, const bf16* __restrict__ h_in,
    float* __restrict__ c_buf, bf16* __restrict__ h_out,
    bf16* __restrict__ hs_t)
{
    const int lane = threadIdx.x & 63, wave = threadIdx.x >> 6;
    const int lo = lane & 15, quad = lane >> 4;
    const int m_base = blockIdx.x*64 + wave*16;
    const int u_base = blockIdx.y*16;
    f32x4 acc[4] = {};
    const int mA = m_base + lo;
    // X part: K = 160 (5 chunks of 32)
    #pragma unroll
    for (int kc = 0; kc < 5; ++kc) {
        const bf16x8 a = *reinterpret_cast<const bf16x8*>(Xt + mA*160 + kc*32 + quad*8);
        #pragma unroll
        for (int g = 0; g < 4; ++g) {
            const bf16x8 bb = *reinterpret_cast<const bf16x8*>(Wih + (g*512 + u_base + lo)*160 + kc*32 + quad*8);
            acc[g] = __builtin_amdgcn_mfma_f32_16x16x32_bf16(a, bb, acc[g], 0, 0, 0);
        }
    }
    // h part: K = 512 (16 chunks of 32)
    #pragma unroll 4
    for (int kc = 0; kc < 16; ++kc) {
        const bf16x8 a = *reinterpret_cast<const bf16x8*>(h_in + mA*512 + kc*32 + quad*8);
        #pragma unroll
        for (int g = 0; g < 4; ++g) {
            const bf16x8 bb = *reinterpret_cast<const bf16x8*>(Whh + (g*512 + u_base + lo)*512 + kc*32 + quad*8);
            acc[g] = __builtin_amdgcn_mfma_f32_16x16x32_bf16(a, bb, acc[g], 0, 0, 0);
        }
    }
    const int u = u_base + lo;
    float bias[4];
    #pragma unroll
    for (int g = 0; g < 4; ++g) bias[g] = bih[g*512+u] + bhh[g*512+u];
    #pragma unroll
    for (int r = 0; r < 4; ++r) {
        const int m = m_base + quad*4 + r;
        const float iv = acc[0][r] + bias[0];
        const float fv = acc[1][r] + bias[1];
        const float gv = acc[2][r] + bias[2];
        const float ov = acc[3][r] + bias[3];
        const int idx = m*512 + u;
        const float c_new = sigm(fv)*c_buf[idx] + sigm(iv)*tanh_f(gv);
        const float hn    = sigm(ov)*tanh_f(c_new);
        c_buf[idx] = c_new;
        h_out[idx] = __float2bfloat16(hn);
        hs_t[idx]  = __float2bfloat16(sigm(hn));   // sigmoid(h) for the linear head
    }
}

// out[b,j] = sigmoid( sum_{t,u} sig_h[t,b,u] * lin_W[j, t*512+u] + lin_b[j] )  -- fp32 output
__global__ __launch_bounds__(256) void k_final(
    const bf16* __restrict__ hs, const float* __restrict__ lW,
    const float* __restrict__ lb, float* __restrict__ out)
{
    const int b = blockIdx.x, tid = threadIdx.x;
    const int u = tid*2;
    float a0=0.f, a1=0.f, a2=0.f, a3=0.f;
    for (int t = 0; t < T_; ++t) {
        const bf16* hr = hs + ((size_t)t*B_ + b)*H_ + u;
        const float h0 = (float)hr[0], h1 = (float)hr[1];
        const int o = t*H_ + u;
        a0 += h0*lW[o]         + h1*lW[o+1];
        a1 += h0*lW[24576+o]   + h1*lW[24576+o+1];
        a2 += h0*lW[49152+o]   + h1*lW[49152+o+1];
        a3 += h0*lW[73728+o]   + h1*lW[73728+o+1];
    }
    #pragma unroll
    for (int off = 32; off > 0; off >>= 1) {
        a0 += __shfl_down(a0, off, 64);
        a1 += __shfl_down(a1, off, 64);
        a2 += __shfl_down(a2, off, 64);
        a3 += __shfl_down(a3, off, 64);
    }
    __shared__ float red[4][4];
    const int wave = tid >> 6, lane = tid & 63;
    if (lane == 0) { red[0][wave]=a0; red[1][wave]=a1; red[2][wave]=a2; red[3][wave]=a3; }
    __syncthreads();
    if (tid < 4) {
        float s = red[tid][0]+red[tid][1]+red[tid][2]+red[tid][3] + lb[tid];
        out[b*4 + tid] = sigm(s);
    }
}

extern "C" void kernel_launch(void* const* d_in, const int* in_sizes, int n_in,
                              void* d_out, int out_size, void* d_ws, size_t ws_size,
                              hipStream_t stream) {
    const float* x   = (const float*)d_in[0];
    const float* ea  = (const float*)d_in[1];
    const float* cW  = (const float*)d_in[2];
    const float* cb  = (const float*)d_in[3];
    const float* gam = (const float*)d_in[4];
    const float* bet = (const float*)d_in[5];
    const float* Wih = (const float*)d_in[6];
    const float* Whh = (const float*)d_in[7];
    const float* bih = (const float*)d_in[8];
    const float* bhh = (const float*)d_in[9];
    const float* lW  = (const float*)d_in[10];
    const float* lb  = (const float*)d_in[11];
    const int*   ei  = (const int*)d_in[12];
    float* out = (float*)d_out;

    // Workspace layout (~73.0 MB total; round-2 run proved ws_size covers it):
    //   [bn_acc 40 KB][Wihb 640 KB][Whhb 2 MB][X 15.7 MB]
    //   [big: y_pre 31.5 MB (phase 1) overlapped by c(2MB)+hA(1MB)+hB(1MB)+hs(50.3MB) (phase 2)]
    char* ws = (char*)d_ws;
    float* bn_acc = (float*)ws;                        // 40960 B
    bf16*  Wihb   = (bf16*)(ws + 40960);               // 655360 B  (2048*160)
    bf16*  Whhb   = (bf16*)(ws + 696320);              // 2097152 B (2048*512)
    bf16*  X      = (bf16*)(ws + 2793472);             // 15728640 B
    char*  big    = ws + 18522112;
    float* y_pre  = (float*)big;                       // phase 1 only (31.5 MB)
    float* c_buf  = (float*)big;                       // phase 2 (after k_bn consumed y_pre)
    bf16*  hA     = (bf16*)(big + 2097152);
    bf16*  hB     = (bf16*)(big + 3145728);
    bf16*  hs     = (bf16*)(big + 4194304);            // 48*1024*512 bf16 = 50331648 B

    k_zero<<<10, 256, 0, stream>>>((float4*)bn_acc, 2560);
    k_cvt<<<320, 256, 0, stream>>>(Wih, Wihb, 2048*160);
    k_cvt<<<1024, 256, 0, stream>>>(Whh, Whhb, 2048*512);
    k_graph<<<NG_, 256, 0, stream>>>(x, ea, cW, cb, ei, y_pre, bn_acc);
    k_bn<<<NF_/256, 256, 0, stream>>>(y_pre, bn_acc, gam, bet, X);
    k_zero<<<768, 256, 0, stream>>>((float4*)c_buf, 196608);   // zero c_buf + hA (3 MB) after y_pre is dead
    for (int t = 0; t < T_; ++t) {
        const bf16* h_in  = (t & 1) ? hB : hA;
        bf16*       h_out = (t & 1) ? hA : hB;
        k_step<<<dim3(16, 32), 256, 0, stream>>>(X + (size_t)t*B_*160, Wihb, Whhb, bih, bhh,
                                                 h_in, c_buf, h_out, hs + (size_t)t*B_*H_);
    }
    k_final<<<B_, 256, 0, stream>>>(hs, lW, lb, out);
}

// Round 4
// 1110.982 us; speedup vs baseline: 1.8899x; 1.8899x over previous
//
#include <hip/hip_runtime.h>
#include <hip/hip_bf16.h>

// ECLGCNN: ChebConv(K=3) on 49152 disjoint 32-node graphs -> per-sample BN ->
// sigmoid -> LSTM(48 steps, H=512) -> linear head. Inputs fp32, output fp32.
// R4: k_graph rebuilt atomic-free (dense 32x32 Laplacian in LDS; fp32 atomicAdd
// lowers to CAS loops -> was 746us @ 3.7% VALU). k_step rebuilt as LDS-staged
// MFMA GEMM (global_load_lds width=16) -> kills 16-line strided fragment loads.

#define B_    1024
#define T_    48
#define NPG_  32
#define F_    5
#define H_    512
#define EPG_  256
#define NG_   (B_*T_)          // 49152 graphs
#define N_    (B_*T_*NPG_)     // 1572864 nodes
#define E_    (B_*T_*EPG_)     // 12582912 edges
#define NF_   (N_*F_)          // 7864320

typedef __bf16 bf16x8 __attribute__((ext_vector_type(8)));
typedef float  f32x4  __attribute__((ext_vector_type(4)));
typedef __hip_bfloat16 bf16;

__device__ __forceinline__ float sigm(float x)   { return 1.0f/(1.0f+__expf(-x)); }
__device__ __forceinline__ float tanh_f(float x) { return 2.0f/(1.0f+__expf(-2.0f*x)) - 1.0f; }

__device__ __forceinline__ void gl_lds16(const void* g, void* l) {
    __builtin_amdgcn_global_load_lds((const __attribute__((address_space(1))) unsigned int*)g,
                                     (__attribute__((address_space(3))) unsigned int*)l, 16, 0, 0);
}

__global__ __launch_bounds__(256) void k_zero(float4* p, int n) {
    int i = blockIdx.x*256 + threadIdx.x;
    if (i < n) p[i] = make_float4(0.f, 0.f, 0.f, 0.f);
}

// Pack W' = [Wih | Whh] row-major [2048][672], fp32 -> bf16.
__global__ __launch_bounds__(256) void k_pack(const float* __restrict__ Wih,
                                              const float* __restrict__ Whh,
                                              bf16* __restrict__ Wp) {
    int i = blockIdx.x*256 + threadIdx.x;           // < 2048*672
    int r = i / 672, c = i - r*672;
    float v = (c < 160) ? Wih[r*160 + c] : Whh[r*512 + (c-160)];
    Wp[i] = __float2bfloat16(v);
}

// One block per 32-node graph; dense-Laplacian formulation, no contended fp atomics.
__global__ __launch_bounds__(256) void k_graph(
    const float* __restrict__ x, const float* __restrict__ ea,
    const float* __restrict__ cW, const float* __restrict__ cb,
    const int* __restrict__ ei, float* __restrict__ y_pre,
    float* __restrict__ part)
{
    const int g = blockIdx.x, tid = threadIdx.x;
    __shared__ float M[32][33];                      // weighted adjacency M[s][d], padded
    __shared__ float dinv[32];
    __shared__ float T0[160], T1[160], T2[160], W[75], bch[5], vbuf[160];
    for (int i = tid; i < 32*33; i += 256) ((float*)M)[i] = 0.f;
    if (tid < 75) W[tid]  = cW[tid];
    if (tid < 5)  bch[tid] = cb[tid];
    if (tid < 160) T0[tid] = x[(size_t)g*160 + tid];
    const int e = g*EPG_ + tid;
    const int s = ei[e] & 31;
    const int d = ei[E_ + e] & 31;
    const float w = ea[e];
    __syncthreads();
    atomicAdd(&M[s][d], w);                          // 256 ops, ~1x contention (dup edges only)
    __syncthreads();
    if (tid < 32) {                                  // deg[s] = row sum of M
        float dg = 0.f;
        #pragma unroll 8
        for (int j = 0; j < 32; ++j) dg += M[tid][j];
        dinv[tid] = dg > 0.f ? rsqrtf(dg) : 0.f;
    }
    __syncthreads();
    // T1[d][f] = -dinv[d] * sum_s M[s][d]*dinv[s]*T0[s][f]
    if (tid < 160) {
        const int dd = tid/5, f = tid - 5*dd;
        float a = 0.f;
        #pragma unroll 8
        for (int ss = 0; ss < 32; ++ss) a += M[ss][dd]*dinv[ss]*T0[ss*5+f];
        T1[tid] = -dinv[dd]*a;
    }
    __syncthreads();
    if (tid < 160) {                                 // T2 = 2 L~ T1 - T0
        const int dd = tid/5, f = tid - 5*dd;
        float a = 0.f;
        #pragma unroll 8
        for (int ss = 0; ss < 32; ++ss) a += M[ss][dd]*dinv[ss]*T1[ss*5+f];
        T2[tid] = -2.f*dinv[dd]*a - T0[tid];
    }
    __syncthreads();
    if (tid < 160) {
        const int n = tid/5, f = tid - 5*n;
        float v = bch[f];
        #pragma unroll
        for (int c = 0; c < 5; ++c)
            v += T0[n*5+c]*W[c*5+f] + T1[n*5+c]*W[25+c*5+f] + T2[n*5+c]*W[50+c*5+f];
        y_pre[(size_t)g*160 + tid] = v;
        vbuf[tid] = v;
    }
    __syncthreads();
    if (tid < 10) {                                  // plain per-graph partial store (no atomics)
        const int f = tid % 5; const bool sq = tid >= 5;
        float sm = 0.f;
        for (int n = 0; n < 32; ++n) { float v = vbuf[n*5+f]; sm += sq ? v*v : v; }
        part[(size_t)g*10 + tid] = sm;
    }
}

// Reduce per-graph partials (48 per sample) -> per-sample BN stats.
__global__ __launch_bounds__(64) void k_stats(const float* __restrict__ part,
                                              float* __restrict__ bn_acc) {
    const int b = blockIdx.x, tid = threadIdx.x;
    if (tid < 10) {
        float s = 0.f;
        for (int j = 0; j < T_; ++j) s += part[((size_t)b*T_ + j)*10 + tid];
        bn_acc[b*10 + tid] = s;
    }
}

// BN apply + sigmoid; writes X (bf16) in [T][B][160].
__global__ __launch_bounds__(256) void k_bn(
    const float* __restrict__ y_pre, const float* __restrict__ bn_acc,
    const float* __restrict__ gamma, const float* __restrict__ beta,
    bf16* __restrict__ X)
{
    const int i = blockIdx.x*256 + threadIdx.x;
    const int b   = i / 7680;
    const int rem = i - b*7680;
    const int t   = rem / 160;
    const int pf  = rem - t*160;
    const int f   = pf % 5;
    const float inv  = 1.0f/1536.0f;
    const float mean = bn_acc[b*10+f]*inv;
    const float var  = bn_acc[b*10+5+f]*inv - mean*mean;
    const float v = gamma[f]*(y_pre[i]-mean)*rsqrtf(var+1e-5f) + beta[f];
    X[((size_t)t*B_ + b)*160 + pf] = __float2bfloat16(sigm(v));
}

// LSTM step, LDS-staged MFMA GEMM. Grid (16,32) = 512 blocks, 128 thr (2 waves).
// Block tile: 64 m-rows x 64 n-rows (n = 4 gates x 16 units, gate-major in LDS so
// nt==gate and the pointwise epilogue fuses per-thread). K streamed in 32-chunks:
// phase 0 reads X_t (row stride 320B, 5 chunks), phase 1 reads h (1024B, 16 chunks).
// W' packed [2048][672] bf16 (row stride 1344B), chunk = global kc index * 64B.
__global__ __launch_bounds__(128) void k_step(
    const bf16* __restrict__ Xt,  const bf16* __restrict__ Wp,
    const float* __restrict__ bih, const float* __restrict__ bhh,
    const bf16* __restrict__ h_in, float* __restrict__ c_buf,
    bf16* __restrict__ h_out, bf16* __restrict__ hs_t)
{
    __shared__ __bf16 A_s[64*32];
    __shared__ __bf16 W_s[64*32];
    const int tid = threadIdx.x;
    const int lane = tid & 63, w = tid >> 6;
    const int lo = lane & 15, quad = lane >> 4;
    const int m0 = blockIdx.x*64;
    const int u0 = blockIdx.y*16;
    f32x4 acc[2][4] = {};

    const char* Wb = (const char*)Wp;
    #pragma unroll
    for (int ph = 0; ph < 2; ++ph) {
        const char* Ab = ph ? (const char*)h_in : (const char*)Xt;
        const int strideA = ph ? 1024 : 320;
        const int nkc = ph ? 16 : 5;
        const int kbase = ph ? 5 : 0;
        for (int kc = 0; kc < nkc; ++kc) {
            __syncthreads();                          // previous chunk fully consumed
            // stage A chunk: 64 rows x 64B (256 granules, 2 per thread)
            #pragma unroll
            for (int i = 0; i < 2; ++i) {
                const int gid = i*128 + tid;
                const int row = gid >> 2, kp = gid & 3;
                gl_lds16(Ab + (size_t)(m0 + row)*strideA + kc*64 + kp*16,
                         (char*)A_s + gid*16);
            }
            // stage W chunk: 64 rows x 64B; LDS row r -> weight row (r>>4)*512 + u0 + (r&15)
            #pragma unroll
            for (int i = 0; i < 2; ++i) {
                const int gid = i*128 + tid;
                const int r = gid >> 2, kp = gid & 3;
                const int wrow = ((r >> 4) << 9) + u0 + (r & 15);
                gl_lds16(Wb + (size_t)wrow*1344 + (kbase + kc)*64 + kp*16,
                         (char*)W_s + gid*16);
            }
            __syncthreads();                          // waits vmcnt(0): LDS data ready
            bf16x8 bfrag[4];
            #pragma unroll
            for (int g = 0; g < 4; ++g)
                bfrag[g] = *reinterpret_cast<const bf16x8*>(&W_s[(g*16 + lo)*32 + quad*8]);
            #pragma unroll
            for (int mt = 0; mt < 2; ++mt) {
                const bf16x8 a = *reinterpret_cast<const bf16x8*>(&A_s[(w*32 + mt*16 + lo)*32 + quad*8]);
                #pragma unroll
                for (int g = 0; g < 4; ++g)
                    acc[mt][g] = __builtin_amdgcn_mfma_f32_16x16x32_bf16(a, bfrag[g], acc[mt][g], 0, 0, 0);
            }
        }
    }
    const int u = u0 + lo;
    float bi[4];
    #pragma unroll
    for (int g = 0; g < 4; ++g) bi[g] = bih[g*512+u] + bhh[g*512+u];
    #pragma unroll
    for (int mt = 0; mt < 2; ++mt) {
        #pragma unroll
        for (int r = 0; r < 4; ++r) {
            const int m = m0 + w*32 + mt*16 + quad*4 + r;
            const float iv = acc[mt][0][r] + bi[0];
            const float fv = acc[mt][1][r] + bi[1];
            const float gv = acc[mt][2][r] + bi[2];
            const float ov = acc[mt][3][r] + bi[3];
            const int idx = m*512 + u;
            const float c_new = sigm(fv)*c_buf[idx] + sigm(iv)*tanh_f(gv);
            const float hn    = sigm(ov)*tanh_f(c_new);
            c_buf[idx] = c_new;
            h_out[idx] = __float2bfloat16(hn);
            hs_t[idx]  = __float2bfloat16(sigm(hn));
        }
    }
}

// out[b,j] = sigmoid( sum_{t,u} sig_h[t,b,u] * lin_W[j, t*512+u] + lin_b[j] )
__global__ __launch_bounds__(256) void k_final(
    const bf16* __restrict__ hs, const float* __restrict__ lW,
    const float* __restrict__ lb, float* __restrict__ out)
{
    const int b = blockIdx.x, tid = threadIdx.x;
    const int u = tid*2;
    float a0=0.f, a1=0.f, a2=0.f, a3=0.f;
    for (int t = 0; t < T_; ++t) {
        const bf16* hr = hs + ((size_t)t*B_ + b)*H_ + u;
        const float h0 = (float)hr[0], h1 = (float)hr[1];
        const int o = t*H_ + u;
        a0 += h0*lW[o]         + h1*lW[o+1];
        a1 += h0*lW[24576+o]   + h1*lW[24576+o+1];
        a2 += h0*lW[49152+o]   + h1*lW[49152+o+1];
        a3 += h0*lW[73728+o]   + h1*lW[73728+o+1];
    }
    #pragma unroll
    for (int off = 32; off > 0; off >>= 1) {
        a0 += __shfl_down(a0, off, 64);
        a1 += __shfl_down(a1, off, 64);
        a2 += __shfl_down(a2, off, 64);
        a3 += __shfl_down(a3, off, 64);
    }
    __shared__ float red[4][4];
    const int wave = tid >> 6, lane = tid & 63;
    if (lane == 0) { red[0][wave]=a0; red[1][wave]=a1; red[2][wave]=a2; red[3][wave]=a3; }
    __syncthreads();
    if (tid < 4) {
        float s = red[tid][0]+red[tid][1]+red[tid][2]+red[tid][3] + lb[tid];
        out[b*4 + tid] = sigm(s);
    }
}

extern "C" void kernel_launch(void* const* d_in, const int* in_sizes, int n_in,
                              void* d_out, int out_size, void* d_ws, size_t ws_size,
                              hipStream_t stream) {
    const float* x   = (const float*)d_in[0];
    const float* ea  = (const float*)d_in[1];
    const float* cW  = (const float*)d_in[2];
    const float* cb  = (const float*)d_in[3];
    const float* gam = (const float*)d_in[4];
    const float* bet = (const float*)d_in[5];
    const float* Wih = (const float*)d_in[6];
    const float* Whh = (const float*)d_in[7];
    const float* bih = (const float*)d_in[8];
    const float* bhh = (const float*)d_in[9];
    const float* lW  = (const float*)d_in[10];
    const float* lb  = (const float*)d_in[11];
    const int*   ei  = (const int*)d_in[12];
    float* out = (float*)d_out;

    // Workspace (73.0 MB, same footprint as round 3 which worked):
    // [bn_acc 40KB][Wp 2.75MB][X 15.7MB][big 54.5MB]
    // big phase 1: y_pre @0 (31.5MB), part @32MB (1.97MB)
    // big phase 2: c @0 (2MB), hA @2MB, hB @3MB, hs @4MB (50.3MB)
    char* ws = (char*)d_ws;
    float* bn_acc = (float*)ws;                        // 40960 B
    bf16*  Wp     = (bf16*)(ws + 40960);               // 2752512 B (2048*672)
    bf16*  X      = (bf16*)(ws + 2793472);             // 15728640 B
    char*  big    = ws + 18522112;
    float* y_pre  = (float*)big;
    float* part   = (float*)(big + 33554432);          // 49152*10*4 = 1966080 B
    float* c_buf  = (float*)big;
    bf16*  hA     = (bf16*)(big + 2097152);
    bf16*  hB     = (bf16*)(big + 3145728);
    bf16*  hs     = (bf16*)(big + 4194304);            // 50331648 B

    k_pack<<<5376, 256, 0, stream>>>(Wih, Whh, Wp);
    k_graph<<<NG_, 256, 0, stream>>>(x, ea, cW, cb, ei, y_pre, part);
    k_stats<<<B_, 64, 0, stream>>>(part, bn_acc);
    k_bn<<<NF_/256, 256, 0, stream>>>(y_pre, bn_acc, gam, bet, X);
    k_zero<<<768, 256, 0, stream>>>((float4*)c_buf, 196608);   // zero c_buf + hA after y_pre dead
    for (int t = 0; t < T_; ++t) {
        const bf16* h_in  = (t & 1) ? hB : hA;
        bf16*       h_out = (t & 1) ? hA : hB;
        k_step<<<dim3(16, 32), 128, 0, stream>>>(X + (size_t)t*B_*160, Wp, bih, bhh,
                                                 h_in, c_buf, h_out, hs + (size_t)t*B_*H_);
    }
    k_final<<<B_, 256, 0, stream>>>(hs, lW, lb, out);
}

// Round 5
// 1018.090 us; speedup vs baseline: 2.0624x; 1.0912x over previous
//
#include <hip/hip_runtime.h>
#include <hip/hip_bf16.h>

// ECLGCNN: ChebConv(K=3) on 49152 disjoint 32-node graphs -> per-sample BN ->
// sigmoid -> LSTM(48 steps, H=512) -> linear head. Inputs fp32, output fp32.
// R5: k_graph graph-per-wave + transposed adjacency (2 LDS reads/MAC, no idle
// threads). k_step 256-thr (2 waves/SIMD) + xor-swizzled LDS staging so
// ds_read_b128 frag reads are bank-conflict-free.

#define B_    1024
#define T_    48
#define NPG_  32
#define F_    5
#define H_    512
#define EPG_  256
#define NG_   (B_*T_)          // 49152 graphs
#define N_    (B_*T_*NPG_)     // 1572864 nodes
#define E_    (B_*T_*EPG_)     // 12582912 edges
#define NF_   (N_*F_)          // 7864320

typedef __bf16 bf16x8 __attribute__((ext_vector_type(8)));
typedef float  f32x4  __attribute__((ext_vector_type(4)));
typedef __hip_bfloat16 bf16;

__device__ __forceinline__ float sigm(float x)   { return 1.0f/(1.0f+__expf(-x)); }
__device__ __forceinline__ float tanh_f(float x) { return 2.0f/(1.0f+__expf(-2.0f*x)) - 1.0f; }

__device__ __forceinline__ void gl_lds16(const void* g, void* l) {
    __builtin_amdgcn_global_load_lds((const __attribute__((address_space(1))) unsigned int*)g,
                                     (__attribute__((address_space(3))) unsigned int*)l, 16, 0, 0);
}

__global__ __launch_bounds__(256) void k_zero(float4* p, int n) {
    int i = blockIdx.x*256 + threadIdx.x;
    if (i < n) p[i] = make_float4(0.f, 0.f, 0.f, 0.f);
}

// Pack W' = [Wih | Whh] row-major [2048][672], fp32 -> bf16.
__global__ __launch_bounds__(256) void k_pack(const float* __restrict__ Wih,
                                              const float* __restrict__ Whh,
                                              bf16* __restrict__ Wp) {
    int i = blockIdx.x*256 + threadIdx.x;           // < 2048*672
    int r = i / 672, c = i - r*672;
    float v = (c < 160) ? Wih[r*160 + c] : Whh[r*512 + (c-160)];
    Wp[i] = __float2bfloat16(v);
}

// Graph-per-wave ChebConv: 4 graphs per 256-thread block.
// Adjacency built TRANSPOSED (Mt[d][s]) so both recursion loops read
// contiguous rows; T-vectors pre-scaled by dinv so inner loop is 2 reads/MAC.
__global__ __launch_bounds__(256) void k_graph(
    const float* __restrict__ x, const float* __restrict__ ea,
    const float* __restrict__ cW, const float* __restrict__ cb,
    const int* __restrict__ ei, float* __restrict__ y_pre,
    float* __restrict__ part)
{
    const int tid = threadIdx.x, w = tid >> 6, lane = tid & 63;
    const int g = blockIdx.x*4 + w;
    __shared__ float Msh[4][1056];                  // Mt[d][s], row stride 33
    __shared__ float dinv[4][32];
    __shared__ float T0s[4][160], T1s[4][160], S0s[4][160], T2s[4][160];
    __shared__ float Wsh[75], bsh[5];
    float* mt = Msh[w];

    if (lane < 75) Wsh[lane] = cW[lane];            // redundant same-value writes: benign
    if (lane < 5)  bsh[lane] = cb[lane];
    const float4 ew = *reinterpret_cast<const float4*>(ea + (size_t)g*256 + lane*4);
    const int4   es = *reinterpret_cast<const int4*>(ei + (size_t)g*256 + lane*4);
    const int4   ed = *reinterpret_cast<const int4*>(ei + (size_t)E_ + (size_t)g*256 + lane*4);
    T0s[w][lane]      = x[(size_t)g*160 + lane];
    T0s[w][64+lane]   = x[(size_t)g*160 + 64 + lane];
    if (lane < 32) T0s[w][128+lane] = x[(size_t)g*160 + 128 + lane];
    for (int i = lane; i < 1056; i += 64) mt[i] = 0.f;
    __syncthreads();
    atomicAdd(&mt[(ed.x & 31)*33 + (es.x & 31)], ew.x);
    atomicAdd(&mt[(ed.y & 31)*33 + (es.y & 31)], ew.y);
    atomicAdd(&mt[(ed.z & 31)*33 + (es.z & 31)], ew.z);
    atomicAdd(&mt[(ed.w & 31)*33 + (es.w & 31)], ew.w);
    __syncthreads();
    if (lane < 32) {                                // deg[s] = sum_d Mt[d][s]
        float dg = 0.f;
        #pragma unroll
        for (int d = 0; d < 32; ++d) dg += mt[d*33 + lane];
        dinv[w][lane] = dg > 0.f ? rsqrtf(dg) : 0.f;
    }
    __syncthreads();
    for (int i = lane; i < 160; i += 64) S0s[w][i] = dinv[w][i/5] * T0s[w][i];
    __syncthreads();
    for (int i = lane; i < 160; i += 64) {          // T1 = -dinv .* (Mt @ S0)
        const int d = i/5, f = i - 5*d;
        float a = 0.f;
        #pragma unroll 8
        for (int s = 0; s < 32; ++s) a += mt[d*33+s] * S0s[w][s*5+f];
        T1s[w][i] = -dinv[w][d]*a;
    }
    __syncthreads();
    for (int i = lane; i < 160; i += 64) S0s[w][i] = dinv[w][i/5] * T1s[w][i];
    __syncthreads();
    for (int i = lane; i < 160; i += 64) {          // T2 = 2 L~ T1 - T0
        const int d = i/5, f = i - 5*d;
        float a = 0.f;
        #pragma unroll 8
        for (int s = 0; s < 32; ++s) a += mt[d*33+s] * S0s[w][s*5+f];
        T2s[w][i] = -2.f*dinv[w][d]*a - T0s[w][i];
    }
    __syncthreads();
    float* vb = mt;                                 // reuse adjacency LDS for y
    for (int i = lane; i < 160; i += 64) {
        const int n = i/5, f = i - 5*n;
        float v = bsh[f];
        #pragma unroll
        for (int c = 0; c < 5; ++c)
            v += T0s[w][n*5+c]*Wsh[c*5+f] + T1s[w][n*5+c]*Wsh[25+c*5+f] + T2s[w][n*5+c]*Wsh[50+c*5+f];
        y_pre[(size_t)g*160 + i] = v;
        vb[i] = v;
    }
    __syncthreads();
    if (lane < 10) {                                // per-graph BN partials
        const int f = lane % 5; const bool sq = lane >= 5;
        float sm = 0.f;
        #pragma unroll 8
        for (int n = 0; n < 32; ++n) { float v = vb[n*5+f]; sm += sq ? v*v : v; }
        part[(size_t)g*10 + lane] = sm;
    }
}

// Reduce per-graph partials (48 per sample) -> per-sample BN stats.
__global__ __launch_bounds__(64) void k_stats(const float* __restrict__ part,
                                              float* __restrict__ bn_acc) {
    const int b = blockIdx.x, tid = threadIdx.x;
    if (tid < 10) {
        float s = 0.f;
        for (int j = 0; j < T_; ++j) s += part[((size_t)b*T_ + j)*10 + tid];
        bn_acc[b*10 + tid] = s;
    }
}

// BN apply + sigmoid; writes X (bf16) in [T][B][160].
__global__ __launch_bounds__(256) void k_bn(
    const float* __restrict__ y_pre, const float* __restrict__ bn_acc,
    const float* __restrict__ gamma, const float* __restrict__ beta,
    bf16* __restrict__ X)
{
    const int i = blockIdx.x*256 + threadIdx.x;
    const int b   = i / 7680;
    const int rem = i - b*7680;
    const int t   = rem / 160;
    const int pf  = rem - t*160;
    const int f   = pf % 5;
    const float inv  = 1.0f/1536.0f;
    const float mean = bn_acc[b*10+f]*inv;
    const float var  = bn_acc[b*10+5+f]*inv - mean*mean;
    const float v = gamma[f]*(y_pre[i]-mean)*rsqrtf(var+1e-5f) + beta[f];
    X[((size_t)t*B_ + b)*160 + pf] = __float2bfloat16(sigm(v));
}

// LSTM step GEMM. Grid (16,32)=512 blocks, 256 thr (4 waves). Block tile
// 64m x 64n (16 units x 4 gates); wave w handles m-rows w*16..w*16+15.
// K streamed in 32-chunks (5 from X_t, 16 from h). Staging via global_load_lds
// width=16 with XOR-swizzle: LDS granule tid holds global granule
// (row=tid>>2, kp=(tid&3)^((tid>>2)&3)) so frag ds_read_b128 is conflict-free.
__global__ __launch_bounds__(256) void k_step(
    const bf16* __restrict__ Xt,  const bf16* __restrict__ Wp,
    const float* __restrict__ bih, const float* __restrict__ bhh,
    const bf16* __restrict__ h_in, float* __restrict__ c_buf,
    bf16* __restrict__ h_out, bf16* __restrict__ hs_t)
{
    __shared__ __bf16 A_s[64*32];
    __shared__ __bf16 W_s[64*32];
    const int tid = threadIdx.x;
    const int lane = tid & 63, w = tid >> 6;
    const int lo = lane & 15, quad = lane >> 4;
    const int m0 = blockIdx.x*64;
    const int u0 = blockIdx.y*16;
    f32x4 acc[4] = {};

    const int srow = tid >> 2;
    const int skp  = (tid & 3) ^ (srow & 3);
    const int wrow = ((srow >> 4) << 9) + u0 + (srow & 15);
    const char* Wg = (const char*)Wp + (size_t)wrow*1344 + skp*16;
    char* Al = (char*)A_s + tid*16;
    char* Wl = (char*)W_s + tid*16;

    const int sw   = (quad ^ (lo & 3)) * 8;          // swizzled frag k-offset
    const int aoff = (w*16 + lo)*32 + sw;

    #pragma unroll
    for (int ph = 0; ph < 2; ++ph) {
        const char* Ag = ph ? (const char*)h_in : (const char*)Xt;
        const int strideA = ph ? 1024 : 320;
        const char* Agp = Ag + (size_t)(m0 + srow)*strideA + skp*16;
        const int nkc = ph ? 16 : 5;
        const int kb  = ph ? 5 : 0;
        for (int kc = 0; kc < nkc; ++kc) {
            __syncthreads();                         // prev chunk fully consumed
            gl_lds16(Agp + kc*64, Al);
            gl_lds16(Wg + (kb + kc)*64, Wl);
            __syncthreads();                         // drains vmcnt: LDS ready
            const bf16x8 a = *reinterpret_cast<const bf16x8*>(&A_s[aoff]);
            #pragma unroll
            for (int g = 0; g < 4; ++g) {
                const bf16x8 bb = *reinterpret_cast<const bf16x8*>(&W_s[(g*16 + lo)*32 + sw]);
                acc[g] = __builtin_amdgcn_mfma_f32_16x16x32_bf16(a, bb, acc[g], 0, 0, 0);
            }
        }
    }
    const int u = u0 + lo;
    const float bI = bih[u]       + bhh[u];
    const float bF = bih[512+u]   + bhh[512+u];
    const float bG = bih[1024+u]  + bhh[1024+u];
    const float bO = bih[1536+u]  + bhh[1536+u];
    #pragma unroll
    for (int r = 0; r < 4; ++r) {
        const int m = m0 + w*16 + quad*4 + r;
        const int idx = m*512 + u;
        const float iv = acc[0][r] + bI;
        const float fv = acc[1][r] + bF;
        const float gv = acc[2][r] + bG;
        const float ov = acc[3][r] + bO;
        const float c_new = sigm(fv)*c_buf[idx] + sigm(iv)*tanh_f(gv);
        const float hn    = sigm(ov)*tanh_f(c_new);
        c_buf[idx] = c_new;
        h_out[idx] = __float2bfloat16(hn);
        hs_t[idx]  = __float2bfloat16(sigm(hn));
    }
}

// out[b,j] = sigmoid( sum_{t,u} sig_h[t,b,u] * lin_W[j, t*512+u] + lin_b[j] )
__global__ __launch_bounds__(256) void k_final(
    const bf16* __restrict__ hs, const float* __restrict__ lW,
    const float* __restrict__ lb, float* __restrict__ out)
{
    const int b = blockIdx.x, tid = threadIdx.x;
    const int u = tid*2;
    float a0=0.f, a1=0.f, a2=0.f, a3=0.f;
    for (int t = 0; t < T_; ++t) {
        const bf16* hr = hs + ((size_t)t*B_ + b)*H_ + u;
        const float h0 = (float)hr[0], h1 = (float)hr[1];
        const int o = t*H_ + u;
        a0 += h0*lW[o]         + h1*lW[o+1];
        a1 += h0*lW[24576+o]   + h1*lW[24576+o+1];
        a2 += h0*lW[49152+o]   + h1*lW[49152+o+1];
        a3 += h0*lW[73728+o]   + h1*lW[73728+o+1];
    }
    #pragma unroll
    for (int off = 32; off > 0; off >>= 1) {
        a0 += __shfl_down(a0, off, 64);
        a1 += __shfl_down(a1, off, 64);
        a2 += __shfl_down(a2, off, 64);
        a3 += __shfl_down(a3, off, 64);
    }
    __shared__ float red[4][4];
    const int wave = tid >> 6, lane = tid & 63;
    if (lane == 0) { red[0][wave]=a0; red[1][wave]=a1; red[2][wave]=a2; red[3][wave]=a3; }
    __syncthreads();
    if (tid < 4) {
        float s = red[tid][0]+red[tid][1]+red[tid][2]+red[tid][3] + lb[tid];
        out[b*4 + tid] = sigm(s);
    }
}

extern "C" void kernel_launch(void* const* d_in, const int* in_sizes, int n_in,
                              void* d_out, int out_size, void* d_ws, size_t ws_size,
                              hipStream_t stream) {
    const float* x   = (const float*)d_in[0];
    const float* ea  = (const float*)d_in[1];
    const float* cW  = (const float*)d_in[2];
    const float* cb  = (const float*)d_in[3];
    const float* gam = (const float*)d_in[4];
    const float* bet = (const float*)d_in[5];
    const float* Wih = (const float*)d_in[6];
    const float* Whh = (const float*)d_in[7];
    const float* bih = (const float*)d_in[8];
    const float* bhh = (const float*)d_in[9];
    const float* lW  = (const float*)d_in[10];
    const float* lb  = (const float*)d_in[11];
    const int*   ei  = (const int*)d_in[12];
    float* out = (float*)d_out;

    // Workspace (73.0 MB):
    // [bn_acc 40KB][Wp 2.75MB][X 15.7MB][big 54.5MB]
    // big phase 1: y_pre @0 (31.5MB), part @32MB (1.97MB)
    // big phase 2: c @0 (2MB), hA @2MB, hB @3MB, hs @4MB (50.3MB)
    char* ws = (char*)d_ws;
    float* bn_acc = (float*)ws;                        // 40960 B
    bf16*  Wp     = (bf16*)(ws + 40960);               // 2752512 B (2048*672)
    bf16*  X      = (bf16*)(ws + 2793472);             // 15728640 B
    char*  big    = ws + 18522112;
    float* y_pre  = (float*)big;
    float* part   = (float*)(big + 33554432);          // 49152*10*4 = 1966080 B
    float* c_buf  = (float*)big;
    bf16*  hA     = (bf16*)(big + 2097152);
    bf16*  hB     = (bf16*)(big + 3145728);
    bf16*  hs     = (bf16*)(big + 4194304);            // 50331648 B

    k_pack<<<5376, 256, 0, stream>>>(Wih, Whh, Wp);
    k_graph<<<NG_/4, 256, 0, stream>>>(x, ea, cW, cb, ei, y_pre, part);
    k_stats<<<B_, 64, 0, stream>>>(part, bn_acc);
    k_bn<<<NF_/256, 256, 0, stream>>>(y_pre, bn_acc, gam, bet, X);
    k_zero<<<768, 256, 0, stream>>>((float4*)c_buf, 196608);   // zero c_buf + hA
    for (int t = 0; t < T_; ++t) {
        const bf16* h_in  = (t & 1) ? hB : hA;
        bf16*       h_out = (t & 1) ? hA : hB;
        k_step<<<dim3(16, 32), 256, 0, stream>>>(X + (size_t)t*B_*160, Wp, bih, bhh,
                                                 h_in, c_buf, h_out, hs + (size_t)t*B_*H_);
    }
    k_final<<<B_, 256, 0, stream>>>(hs, lW, lb, out);
}